// Round 14
// baseline (258.925 us; speedup 1.0000x reference)
//
#include <hip/hip_runtime.h>

// N=50000, E=800000, Q=200000, d_in=64, h=128
// bf16 random-access features; split-bf16 MFMA; atomic-free CSR fill (HB=64);
// fusions: hist+xb+fold (k_pre); reduce+scan+block-placement (k_rs, no global
// scan kernels -- segments placed via one atomicAdd per 512-node block).

#define HB 64       // histogram / fill chunks
#define NWIN 16384  // node/word window (64KB LDS)

typedef __attribute__((ext_vector_type(8))) short short8;
typedef __attribute__((ext_vector_type(4))) float floatx4;

static __device__ __forceinline__ unsigned int f2bf(float v) {
    union { float f; unsigned int u; } c; c.f = v;
    unsigned int lsb = (c.u >> 16) & 1u;
    c.u += 0x7FFFu + lsb;                 // round-to-nearest-even
    return c.u >> 16;
}
static __device__ __forceinline__ float bf2f(unsigned int h) {
    union { float f; unsigned int u; } c; c.u = h << 16;
    return c.f;
}

// ---------- fused prologue: histogram + x->bf16 + weight fold/pack ----------
__global__ __launch_bounds__(256) void k_pre(const int* __restrict__ row,
                                             const int* __restrict__ col,
                                             unsigned int* __restrict__ hRow,
                                             unsigned int* __restrict__ hCol,
                                             const float* __restrict__ x,
                                             unsigned int* __restrict__ xb,
                                             const float* __restrict__ W1,
                                             const float* __restrict__ W2,
                                             const float* __restrict__ Wc1,
                                             const float* __restrict__ b2,
                                             const float* __restrict__ bc1,
                                             unsigned short* __restrict__ UVhi,
                                             unsigned short* __restrict__ UVlo,
                                             unsigned short* __restrict__ W1hi,
                                             unsigned short* __restrict__ W1lo,
                                             float* __restrict__ buv,
                                             int* __restrict__ gCnt,
                                             int E, int N, int W, int chunk,
                                             int nHist, int nXb) {
    __shared__ unsigned int lds[NWIN];
    int t = threadIdx.x, b = blockIdx.x;
    if (b == 0 && t == 0) *gCnt = 0;   // base counter for k_rs placement
    if (b < nHist) {
        int hb = b % HB;
        int yb = b / HB;
        int p = yb >> 1, win = yb & 1;
        int base = win * NWIN;
        int wcap = min(W - base, NWIN);
        if (wcap <= 0) return;
        const int* idxArr = p ? col : row;
        unsigned int* outArr = p ? hCol : hRow;
        int e0 = hb * chunk, e1 = min(E, e0 + chunk);
        for (int i = t; i < wcap; i += 256) lds[i] = 0;
        __syncthreads();
        for (int e = e0 + t; e < e1; e += 256) {
            int idx = idxArr[e];
            int w = (idx >> 1) - base;
            if ((unsigned)w < (unsigned)wcap)
                atomicAdd(&lds[w], 1u << ((idx & 1) * 16));
        }
        __syncthreads();
        for (int i = t; i < wcap; i += 256)
            outArr[(size_t)hb * W + base + i] = lds[i];
    } else if (b < nHist + nXb) {
        int i = (b - nHist) * 256 + t;
        if (i < N * 32) {
            float2 v = ((const float2*)x)[i];
            xb[i] = f2bf(v.x) | (f2bf(v.y) << 16);
        }
    } else {
        int bf = b - nHist - nXb;
        float* w2row = (float*)lds;
        if (bf < 128) {
            int k = bf;
            int j = t & 127, half = t >> 7;
            int n = half * 128 + j;
            const float* wc = Wc1 + (size_t)half * 128 * 128 + j;
            if (t < 128) w2row[t] = W2[k * 128 + t];
            __syncthreads();
            float acc = 0.f;
#pragma unroll 8
            for (int m = 0; m < 128; m++) acc += w2row[m] * wc[(size_t)m * 128];
            int kstep = k >> 5, kl = k & 31, quad = kl >> 3, j8 = kl & 7;
            int nb = n >> 4, l = quad * 16 + (n & 15);
            int pidx = ((kstep * 16 + nb) * 64 + l) * 8 + j8;
            unsigned int h = f2bf(acc);
            UVhi[pidx] = (unsigned short)h;
            UVlo[pidx] = (unsigned short)f2bf(acc - bf2f(h));
        } else if (bf == 128) {
            int j = t & 127, half = t >> 7;
            const float* wc = Wc1 + (size_t)half * 128 * 128 + j;
            float acc = half ? 0.f : bc1[j];
#pragma unroll 8
            for (int m = 0; m < 128; m++) acc += b2[m] * wc[(size_t)m * 128];
            buv[half * 128 + j] = acc;
        } else {
            int idx = (bf - 129) * 256 + t;  // < 8192
            int k = idx >> 7, n = idx & 127;
            float v = W1[k * 128 + n];
            int kstep = k >> 5, kl = k & 31, quad = kl >> 3, j8 = kl & 7;
            int nb = n >> 4, l = quad * 16 + (n & 15);
            int pidx = ((kstep * 8 + nb) * 64 + l) * 8 + j8;
            unsigned int h = f2bf(v);
            W1hi[pidx] = (unsigned short)h;
            W1lo[pidx] = (unsigned short)f2bf(v - bf2f(h));
        }
    }
}

// ---------- fused reduce + local scan + atomic block placement ----------
// Per word w (2 nodes): sum HB partials -> deg(row), cnt(col); replace hCol
// with per-block exclusive prefix; emit dis. Block-scan the 512 node counts,
// claim a global base via one atomicAdd, write starts[]/ends[].
// (CSR segments need not be in node order -- only disjoint and sized right.)
__global__ __launch_bounds__(256) void k_rs(const unsigned int* __restrict__ hRow,
                                            unsigned int* __restrict__ hCol,
                                            float* __restrict__ dis,
                                            int* __restrict__ starts,
                                            int* __restrict__ ends,
                                            int* __restrict__ gCnt,
                                            int N, int W) {
    __shared__ int ts[256];
    __shared__ int blockBase;
    int t = threadIdx.x;
    int w = blockIdx.x * 256 + t;
    unsigned int r0 = 0, r1 = 0, c0 = 0, c1 = 0;
    if (w < W) {
#pragma unroll 8
        for (int b = 0; b < HB; b++) {
            size_t idx = (size_t)b * W + w;
            unsigned int hr = hRow[idx];
            unsigned int hc = hCol[idx];
            hCol[idx] = c0 | (c1 << 16);   // exclusive prefix over blocks
            r0 += hr & 0xFFFFu; r1 += hr >> 16;
            c0 += hc & 0xFFFFu; c1 += hc >> 16;
        }
        int n0 = 2 * w, n1 = 2 * w + 1;
        dis[n0] = 1.0f / sqrtf((float)(r0 + 1));
        if (n1 < N) dis[n1] = 1.0f / sqrtf((float)(r1 + 1));
    }
    int sum = (w < W) ? (int)(c0 + c1) : 0;
    ts[t] = sum;
    __syncthreads();
    for (int off = 1; off < 256; off <<= 1) {
        int xv = (t >= off) ? ts[t - off] : 0;
        __syncthreads();
        ts[t] += xv;
        __syncthreads();
    }
    if (t == 255) blockBase = atomicAdd(gCnt, ts[255]);
    __syncthreads();
    int e = ts[t] - sum + blockBase;  // this word's segment start
    if (w < W) {
        int n0 = 2 * w, n1 = 2 * w + 1;
        starts[n0] = e;
        ends[n0] = e + (int)c0;
        if (n1 < N) {
            starts[n1] = e + (int)c0;
            ends[n1] = e + (int)(c0 + c1);
        }
    }
}

// ---------- CSR fill, atomic-free, 2D grid ----------
__global__ __launch_bounds__(256) void k_fill3(const int* __restrict__ row,
                                               const int* __restrict__ col,
                                               const int* __restrict__ starts,
                                               const unsigned int* __restrict__ hCol,
                                               int* __restrict__ srcSorted,
                                               int E, int N, int W, int chunk) {
    __shared__ int base[NWIN];
    int t = threadIdx.x, b = blockIdx.x;
    int n0 = blockIdx.y * NWIN;
    int nCnt = min(NWIN, N - n0);
    int e0 = b * chunk, e1 = min(E, e0 + chunk);
    for (int wl = t; wl * 2 < nCnt; wl += 256) {
        unsigned int pref = hCol[(size_t)b * W + (n0 >> 1) + wl];
        int nn = n0 + wl * 2;
        base[wl * 2] = starts[nn] + (int)(pref & 0xFFFFu);
        if (wl * 2 + 1 < nCnt)
            base[wl * 2 + 1] = starts[nn + 1] + (int)(pref >> 16);
    }
    __syncthreads();
    for (int e = e0 + t; e < e1; e += 256) {
        int c = col[e] - n0;
        if ((unsigned)c < (unsigned)nCnt) {
            int pos = atomicAdd(&base[c], 1);
            srcSorted[pos] = row[e];
        }
    }
}

// ---------- fused conv1: gather(d=64) -> LDS split-bf16 -> MFMA -> h1b ----------
// 16 nodes/block (grid = N/16: full gather parallelism).
__global__ __launch_bounds__(256) void k_conv1(const unsigned short* __restrict__ s,
                                               const int* __restrict__ starts,
                                               const int* __restrict__ ends,
                                               const int* __restrict__ srcs,
                                               const float* __restrict__ dis,
                                               const unsigned short* __restrict__ Bhi,
                                               const unsigned short* __restrict__ Blo,
                                               const float* __restrict__ b1,
                                               unsigned short* __restrict__ h1b, int N) {
    __shared__ unsigned short Ahi[16][72];
    __shared__ unsigned short Alo[16][72];
    int t = threadIdx.x;
    int lane = t & 63, wave = t >> 6;
    int quad = lane >> 4;
    short8 bh[2][2], bl[2][2];
#pragma unroll
    for (int ks = 0; ks < 2; ks++)
#pragma unroll
        for (int nt = 0; nt < 2; nt++) {
            int nb = wave * 2 + nt;
            bh[ks][nt] = *(const short8*)(Bhi + ((ks * 8 + nb) * 64 + lane) * 8);
            bl[ks][nt] = *(const short8*)(Blo + ((ks * 8 + nb) * 64 + lane) * 8);
        }
    {
        int nl = t >> 4;
        int node = blockIdx.x * 16 + nl;
        if (node < N) {
            int c4 = (t & 15) * 4;
            int e = starts[node], eEnd = ends[node];
            float dn = dis[node];
            uint2 w = *(const uint2*)(s + (size_t)node * 64 + c4);
            float4 acc;
            acc.x = bf2f(w.x & 0xFFFF) * dn; acc.y = bf2f(w.x >> 16) * dn;
            acc.z = bf2f(w.y & 0xFFFF) * dn; acc.w = bf2f(w.y >> 16) * dn;
            while (e + 1 < eEnd) {
                int sA = srcs[e], sB = srcs[e + 1];
                float dA = dis[sA], dB = dis[sB];
                uint2 vA = *(const uint2*)(s + (size_t)sA * 64 + c4);
                uint2 vB = *(const uint2*)(s + (size_t)sB * 64 + c4);
                acc.x += bf2f(vA.x & 0xFFFF) * dA + bf2f(vB.x & 0xFFFF) * dB;
                acc.y += bf2f(vA.x >> 16) * dA + bf2f(vB.x >> 16) * dB;
                acc.z += bf2f(vA.y & 0xFFFF) * dA + bf2f(vB.y & 0xFFFF) * dB;
                acc.w += bf2f(vA.y >> 16) * dA + bf2f(vB.y >> 16) * dB;
                e += 2;
            }
            if (e < eEnd) {
                int sA = srcs[e];
                float dA = dis[sA];
                uint2 vA = *(const uint2*)(s + (size_t)sA * 64 + c4);
                acc.x += bf2f(vA.x & 0xFFFF) * dA; acc.y += bf2f(vA.x >> 16) * dA;
                acc.z += bf2f(vA.y & 0xFFFF) * dA; acc.w += bf2f(vA.y >> 16) * dA;
            }
            acc.x *= dn; acc.y *= dn; acc.z *= dn; acc.w *= dn;
            unsigned int h0 = f2bf(acc.x), h1 = f2bf(acc.y),
                         h2 = f2bf(acc.z), h3 = f2bf(acc.w);
            uint2 hw; hw.x = h0 | (h1 << 16); hw.y = h2 | (h3 << 16);
            uint2 lw;
            lw.x = f2bf(acc.x - bf2f(h0)) | (f2bf(acc.y - bf2f(h1)) << 16);
            lw.y = f2bf(acc.z - bf2f(h2)) | (f2bf(acc.w - bf2f(h3)) << 16);
            *(uint2*)(&Ahi[nl][c4]) = hw;
            *(uint2*)(&Alo[nl][c4]) = lw;
        }
    }
    __syncthreads();
    int ml = lane & 15;
    floatx4 acc[2] = {};
#pragma unroll
    for (int ks = 0; ks < 2; ks++) {
        short8 ahi = *(const short8*)(&Ahi[ml][ks * 32 + quad * 8]);
        short8 alo = *(const short8*)(&Alo[ml][ks * 32 + quad * 8]);
#pragma unroll
        for (int nt = 0; nt < 2; nt++) {
            acc[nt] = __builtin_amdgcn_mfma_f32_16x16x32_bf16(ahi, bh[ks][nt], acc[nt], 0, 0, 0);
            acc[nt] = __builtin_amdgcn_mfma_f32_16x16x32_bf16(ahi, bl[ks][nt], acc[nt], 0, 0, 0);
            acc[nt] = __builtin_amdgcn_mfma_f32_16x16x32_bf16(alo, bh[ks][nt], acc[nt], 0, 0, 0);
        }
    }
    int md = blockIdx.x * 16 + quad * 4;
#pragma unroll
    for (int nt = 0; nt < 2; nt++) {
        int n0 = (wave * 2 + nt) * 16 + (lane & 15);
        float bias = b1[n0];
#pragma unroll
        for (int r = 0; r < 4; r++) {
            int node = md + r;
            if (node < N)
                h1b[(size_t)node * 128 + n0] =
                    (unsigned short)f2bf(fmaxf(acc[nt][r] + bias, 0.f) * dis[node]);
        }
    }
}

// ---------- conv2 gather: bf16 h1 in, bf16 agg2 out (d=128, 16 lanes/node) ----------
__global__ __launch_bounds__(256) void k_gather2(const unsigned short* __restrict__ s,
                                                 const int* __restrict__ starts,
                                                 const int* __restrict__ ends,
                                                 const int* __restrict__ srcs,
                                                 const float* __restrict__ dis,
                                                 unsigned short* __restrict__ agg,
                                                 int N) {
    int tid = blockIdx.x * 256 + threadIdx.x;
    int node = tid >> 4;
    if (node >= N) return;
    int c8 = (tid & 15) * 8;
    int e = starts[node], eEnd = ends[node];
    float dn = dis[node];
    uint4 w = *(const uint4*)(s + (size_t)node * 128 + c8);
    float a0 = bf2f(w.x & 0xFFFF), a1 = bf2f(w.x >> 16);
    float a2 = bf2f(w.y & 0xFFFF), a3 = bf2f(w.y >> 16);
    float a4 = bf2f(w.z & 0xFFFF), a5 = bf2f(w.z >> 16);
    float a6 = bf2f(w.w & 0xFFFF), a7 = bf2f(w.w >> 16);
    while (e + 1 < eEnd) {
        int sA = srcs[e], sB = srcs[e + 1];
        uint4 vA = *(const uint4*)(s + (size_t)sA * 128 + c8);
        uint4 vB = *(const uint4*)(s + (size_t)sB * 128 + c8);
        a0 += bf2f(vA.x & 0xFFFF) + bf2f(vB.x & 0xFFFF);
        a1 += bf2f(vA.x >> 16) + bf2f(vB.x >> 16);
        a2 += bf2f(vA.y & 0xFFFF) + bf2f(vB.y & 0xFFFF);
        a3 += bf2f(vA.y >> 16) + bf2f(vB.y >> 16);
        a4 += bf2f(vA.z & 0xFFFF) + bf2f(vB.z & 0xFFFF);
        a5 += bf2f(vA.z >> 16) + bf2f(vB.z >> 16);
        a6 += bf2f(vA.w & 0xFFFF) + bf2f(vB.w & 0xFFFF);
        a7 += bf2f(vA.w >> 16) + bf2f(vB.w >> 16);
        e += 2;
    }
    if (e < eEnd) {
        int sA = srcs[e];
        uint4 vA = *(const uint4*)(s + (size_t)sA * 128 + c8);
        a0 += bf2f(vA.x & 0xFFFF); a1 += bf2f(vA.x >> 16);
        a2 += bf2f(vA.y & 0xFFFF); a3 += bf2f(vA.y >> 16);
        a4 += bf2f(vA.z & 0xFFFF); a5 += bf2f(vA.z >> 16);
        a6 += bf2f(vA.w & 0xFFFF); a7 += bf2f(vA.w >> 16);
    }
    uint4 o;
    o.x = f2bf(a0 * dn) | (f2bf(a1 * dn) << 16);
    o.y = f2bf(a2 * dn) | (f2bf(a3 * dn) << 16);
    o.z = f2bf(a4 * dn) | (f2bf(a5 * dn) << 16);
    o.w = f2bf(a6 * dn) | (f2bf(a7 * dn) << 16);
    *(uint4*)(agg + (size_t)node * 128 + c8) = o;
}

// ---------- MFMA GEMM UV: [Ub|Vb] = bf16(agg2b @ Wfull + buv) ----------
__global__ __launch_bounds__(256) void k_mfmaUV(const unsigned short* __restrict__ A,
                                                const unsigned short* __restrict__ Bhi,
                                                const unsigned short* __restrict__ Blo,
                                                const float* __restrict__ buv,
                                                unsigned short* __restrict__ Ub,
                                                unsigned short* __restrict__ Vb, int N) {
    int lane = threadIdx.x & 63, wave = threadIdx.x >> 6;
    int quad = lane >> 4;
    short8 bh[4][4], bl[4][4];
#pragma unroll
    for (int ks = 0; ks < 4; ks++)
#pragma unroll
        for (int nt = 0; nt < 4; nt++) {
            int nb = wave * 4 + nt;
            bh[ks][nt] = *(const short8*)(Bhi + ((ks * 16 + nb) * 64 + lane) * 8);
            bl[ks][nt] = *(const short8*)(Blo + ((ks * 16 + nb) * 64 + lane) * 8);
        }
#pragma unroll
    for (int g = 0; g < 4; g++) {
        int mbase = blockIdx.x * 64 + g * 16;
        int ma = mbase + (lane & 15); if (ma >= N) ma = N - 1;
        floatx4 acc[4] = {};
#pragma unroll
        for (int ks = 0; ks < 4; ks++) {
            short8 a = *(const short8*)(A + (size_t)ma * 128 + ks * 32 + quad * 8);
#pragma unroll
            for (int nt = 0; nt < 4; nt++) {
                acc[nt] = __builtin_amdgcn_mfma_f32_16x16x32_bf16(a, bh[ks][nt], acc[nt], 0, 0, 0);
                acc[nt] = __builtin_amdgcn_mfma_f32_16x16x32_bf16(a, bl[ks][nt], acc[nt], 0, 0, 0);
            }
        }
        int md = mbase + quad * 4;
#pragma unroll
        for (int nt = 0; nt < 4; nt++) {
            int n0 = wave * 64 + nt * 16 + (lane & 15);
            float bias = buv[n0];
            unsigned short* dst = (n0 < 128) ? Ub : Vb;
            int cc = n0 & 127;
#pragma unroll
            for (int r = 0; r < 4; r++) {
                int node = md + r;
                if (node < N)
                    dst[(size_t)node * 128 + cc] =
                        (unsigned short)f2bf(acc[nt][r] + bias);
            }
        }
    }
}

// ---------- head: out[q] = relu(Ub[src]+Vb[dst]) . Wc2 + bc2 ----------
__global__ __launch_bounds__(256) void k_head(const unsigned short* __restrict__ Ub,
                                              const unsigned short* __restrict__ Vb,
                                              const int* __restrict__ srcA,
                                              const int* __restrict__ dstA,
                                              const float* __restrict__ Wc2,
                                              const float* __restrict__ bc2,
                                              float* __restrict__ out, int Q) {
    int t = threadIdx.x;
    int q = blockIdx.x * 16 + (t >> 4);
    if (q >= Q) return;
    int l = t & 15;
    int s = srcA[q], d = dstA[q];
    uint4 u = *(const uint4*)(Ub + (size_t)s * 128 + l * 8);
    uint4 v = *(const uint4*)(Vb + (size_t)d * 128 + l * 8);
    const float4* w = (const float4*)(Wc2 + l * 8);
    float4 w0 = w[0], w1 = w[1];
    float acc = 0.f, z;
    z = fmaxf(bf2f(u.x & 0xFFFF) + bf2f(v.x & 0xFFFF), 0.f); acc += z * w0.x;
    z = fmaxf(bf2f(u.x >> 16)    + bf2f(v.x >> 16),    0.f); acc += z * w0.y;
    z = fmaxf(bf2f(u.y & 0xFFFF) + bf2f(v.y & 0xFFFF), 0.f); acc += z * w0.z;
    z = fmaxf(bf2f(u.y >> 16)    + bf2f(v.y >> 16),    0.f); acc += z * w0.w;
    z = fmaxf(bf2f(u.z & 0xFFFF) + bf2f(v.z & 0xFFFF), 0.f); acc += z * w1.x;
    z = fmaxf(bf2f(u.z >> 16)    + bf2f(v.z >> 16),    0.f); acc += z * w1.y;
    z = fmaxf(bf2f(u.w & 0xFFFF) + bf2f(v.w & 0xFFFF), 0.f); acc += z * w1.z;
    z = fmaxf(bf2f(u.w >> 16)    + bf2f(v.w >> 16),    0.f); acc += z * w1.w;
    acc += __shfl_xor(acc, 1);
    acc += __shfl_xor(acc, 2);
    acc += __shfl_xor(acc, 4);
    acc += __shfl_xor(acc, 8);
    if (l == 0) out[q] = acc + bc2[0];
}

extern "C" void kernel_launch(void* const* d_in, const int* in_sizes, int n_in,
                              void* d_out, int out_size, void* d_ws, size_t ws_size,
                              hipStream_t stream) {
    const float* x   = (const float*)d_in[0];
    const int*   ei  = (const int*)d_in[1];
    const int*   eli = (const int*)d_in[2];
    const float* W1  = (const float*)d_in[3];
    const float* b1  = (const float*)d_in[4];
    const float* W2  = (const float*)d_in[5];
    const float* b2  = (const float*)d_in[6];
    const float* Wc1 = (const float*)d_in[7];
    const float* bc1 = (const float*)d_in[8];
    const float* Wc2 = (const float*)d_in[9];
    const float* bc2 = (const float*)d_in[10];
    float* out = (float*)d_out;
    char* wsb = (char*)d_ws;

    const int N = in_sizes[0] / 64;
    const int E = in_sizes[1] / 2;
    const int Q = in_sizes[2] / 2;
    const int W = (N + 1) / 2;
    const int chunk = (E + HB - 1) / HB;
    const int nPass = (N + NWIN - 1) / NWIN;   // fill windows (nodes)
    const int nWinH = (W + NWIN - 1) / NWIN;   // hist windows (words)
    const int nHist = HB * 2 * nWinH;
    const int nXb   = (N * 32 + 255) / 256;
    const int rsB   = (W + 255) / 256;         // k_rs blocks (512 nodes each)

    // workspace layout (word offsets, 4B units)
    float* dis       = (float*)wsb;                                // 65536
    int*   starts    = (int*)wsb + 65536;                          // N
    int*   ends      = (int*)wsb + 131072;                         // N
    int*   gCnt      = (int*)wsb + 196608;                         // 1
    float* buv       = (float*)wsb + 262912;                       // 256
    unsigned short* UVhi = (unsigned short*)((int*)wsb + 263168);  // 32768 us
    unsigned short* UVlo = (unsigned short*)((int*)wsb + 279552);
    unsigned short* W1hi = (unsigned short*)((int*)wsb + 295936);  // 8192 us
    unsigned short* W1lo = (unsigned short*)((int*)wsb + 300032);
    int*   srcSorted = (int*)wsb + 304128;                         // E -> 1104128
    unsigned short* Vb   = (unsigned short*)((int*)wsb + 1104128); // N*128 us -> 4304128
    unsigned short* h1b  = (unsigned short*)((int*)wsb + 4304128); // N*128 us -> 7504128
    unsigned short* agg2b= (unsigned short*)((int*)wsb + 7504128); // N*128 us -> 10704128
    unsigned short* Ub = h1b;                                      // overlays dead h1b
    unsigned int* hRow = (unsigned int*)wsb + 10704128;            // HB*W -> 12304128
    unsigned int* hCol = (unsigned int*)wsb + 12304128;            // HB*W -> 13904128
    unsigned int* xb   = (unsigned int*)wsb + 13904128;            // N*32 words -> 15504128

    const int* row  = ei;
    const int* col  = ei + E;
    const int* srcA = eli;
    const int* dstA = eli + Q;

    k_pre<<<nHist + nXb + 161, 256, 0, stream>>>(
        row, col, hRow, hCol, x, xb, W1, W2, Wc1, b2, bc1,
        UVhi, UVlo, W1hi, W1lo, buv, gCnt, E, N, W, chunk, nHist, nXb);
    k_rs<<<rsB, 256, 0, stream>>>(hRow, hCol, dis, starts, ends, gCnt, N, W);
    k_fill3<<<dim3(HB, nPass), 256, 0, stream>>>(row, col, starts, hCol, srcSorted, E, N, W, chunk);
    k_conv1<<<(N + 15) / 16, 256, 0, stream>>>(
        (const unsigned short*)xb, starts, ends, srcSorted, dis, W1hi, W1lo, b1, h1b, N);
    k_gather2<<<((size_t)N * 16 + 255) / 256, 256, 0, stream>>>(
        h1b, starts, ends, srcSorted, dis, agg2b, N);
    k_mfmaUV<<<(N + 63) / 64, 256, 0, stream>>>(agg2b, UVhi, UVlo, buv, Ub, Vb, N);
    k_head<<<(Q + 15) / 16, 256, 0, stream>>>(Ub, Vb, srcA, dstA, Wc2, bc2, out, Q);
}